// Round 5
// baseline (9919.481 us; speedup 1.0000x reference)
//
#include <hip/hip_runtime.h>
#include <cmath>

#define HID 1024
#define NB  128   // batch
#define NT  512   // seq len
#define NV  128   // vocab
#define NBLK 256  // persistent RNN blocks: 8 bg x 32 cg

using u16 = unsigned short;
using u32 = unsigned int;

typedef __attribute__((ext_vector_type(8))) short s16x8;
typedef __attribute__((ext_vector_type(4))) float f32x4;

static __device__ __forceinline__ float bf2f(u16 u) {
  union { u32 i; float f; } v; v.i = ((u32)u) << 16; return v.f;
}
static __device__ __forceinline__ u16 f2bf(float f) {
  union { u32 i; float f; } v; v.f = f;
  u32 r = v.i + 0x7FFFu + ((v.i >> 16) & 1u);   // round-to-nearest-even
  return (u16)(r >> 16);
}

// ---------------------------------------------------------------------------
// Persistent RNN, all 512 steps. Block (bg,cg): 16 batches x 32 cols.
//   bg = blk & 7  -> under round-robin dispatch, all 32 blocks of a bg share
//                    one XCD: h-exchange + barrier stay L2-local.
// Whh col-slice in LDS (bf16, transposed, XOR-swizzled). Per step:
//   S[16x32] = h_prev(global bf16 dbuf) @ WtLDS via mfma 16x16x32 (f32 acc)
//   h = tanhf(S + Wxh[x_t] + bh), publish to dbuf, archive to Hs.
// Barrier: per-bg counter (32 participants), release-add + acquire-spin on
// tid0 (primitives identical to the validated round-4 kernel). Hs archive +
// next-step Wxh prefetch are issued AFTER the release so they overlap the
// spin; xe lives in 4 registers (no LDS, no post-barrier L2 gather).
// ---------------------------------------------------------------------------
__global__ __launch_bounds__(128, 1) void rnn_persist(
    const int* __restrict__ x, const float* __restrict__ Wxh,
    const float* __restrict__ Whh, const float* __restrict__ bh,
    u16* __restrict__ Hs, u16* __restrict__ hbuf, u32* __restrict__ ctr)
{
  const int blk  = blockIdx.x;
  const int bg   = blk & 7;         // XCD-local batch group
  const int cg   = blk >> 3;        // 0..31 col group
  const int tid  = threadIdx.x;     // 0..127 (2 waves)
  const int wave = tid >> 6;
  const int lane = tid & 63;
  const int b0   = bg * 16;
  const int c0   = cg * 32;

  __shared__ u16 Wt[32 * 1024];     // [col][k] bf16, byte-XOR-swizzled

  // ---- stage Wt (transpose Whh[k][c0+col] -> Wt[col][k], bf16, swizzle) ----
  for (int it = 0; it < 128; ++it) {
    int idx = tid + it * 128;       // 0..16383
    int col = idx & 31;
    int k   = (idx >> 5) * 2;       // k pair
    float w0 = Whh[(size_t)k * HID + c0 + col];
    float w1 = Whh[(size_t)(k + 1) * HID + c0 + col];
    u32 pk = ((u32)f2bf(w1) << 16) | (u32)f2bf(w0);
    u32 byteo = ((u32)col * 2048 + (u32)k * 2) ^ ((u32)(col & 7) << 4);
    *reinterpret_cast<u32*>(reinterpret_cast<char*>(Wt) + byteo) = pk;
  }

  // MFMA fragment geometry (16x16x32 bf16):
  //   A: row = lane&15 (batch m), k-slice = (lane>>4)*8
  //   B: col = lane&15 (out col n), k-slice = (lane>>4)*8
  //   C: n = lane&15, m = (lane>>4)*4 + reg
  const int frow = lane & 15;
  const int koff = (lane >> 4) * 8;
  const int col  = wave * 16 + (lane & 15);
  const int cc   = c0 + col;
  const u32 swz   = (u32)(col & 7) << 4;
  const u32 bbase = (u32)col * 2048 + (u32)koff * 2;
  const char* wtb = reinterpret_cast<const char*>(Wt);

  // bh is col-invariant per thread; xe for step 0 prefetched into registers
  const float bhv = bh[cc];
  float xr[4];
  #pragma unroll
  for (int r = 0; r < 4; ++r) {
    int m = (lane >> 4) * 4 + r;
    int xt = x[(size_t)(b0 + m) * NT];
    xr[r] = Wxh[(size_t)xt * HID + cc] + bhv;
  }
  __syncthreads();                  // Wt ready

  u32* __restrict__ myctr = ctr + bg * 64;   // 256 B apart per bg

  for (int t = 0; t < NT; ++t) {
    // ---- S = h_prev @ Wslice via MFMA (K = 1024 = 32 chunks) ----
    f32x4 acc = {0.f, 0.f, 0.f, 0.f};
    if (t > 0) {
      const u16* hprev = hbuf + (size_t)(t & 1) * NB * HID;
      const u16* ap = hprev + (size_t)(b0 + frow) * HID + koff;
      #pragma unroll 8
      for (int kc = 0; kc < 32; ++kc) {
        s16x8 af = *reinterpret_cast<const s16x8*>(ap + kc * 32);
        s16x8 bf = *reinterpret_cast<const s16x8*>(wtb + ((bbase + (u32)kc * 64) ^ swz));
        acc = __builtin_amdgcn_mfma_f32_16x16x32_bf16(af, bf, acc, 0, 0, 0);
      }
    }

    // ---- epilogue: tanh, publish h_t to dbuf ----
    u16* hnext = hbuf + (size_t)((t + 1) & 1) * NB * HID;
    u16 hb[4];
    #pragma unroll
    for (int r = 0; r < 4; ++r) {
      int m = (lane >> 4) * 4 + r;
      float h = tanhf(acc[r] + xr[r]);
      hb[r] = f2bf(h);
      hnext[(size_t)(b0 + m) * HID + cc] = hb[r];
    }
    __syncthreads();   // all hnext stores drained (vmcnt0 before s_barrier)

    if (tid == 0 && t < NT - 1)
      __hip_atomic_fetch_add(myctr, 1u, __ATOMIC_RELEASE, __HIP_MEMORY_SCOPE_AGENT);

    // ---- overlap the spin: archive Hs + prefetch next xe ----
    #pragma unroll
    for (int r = 0; r < 4; ++r) {
      int m = (lane >> 4) * 4 + r;
      Hs[((size_t)(b0 + m) * NT + t) * HID + cc] = hb[r];
    }
    if (t < NT - 1) {
      #pragma unroll
      for (int r = 0; r < 4; ++r) {
        int m = (lane >> 4) * 4 + r;
        int xt = x[(size_t)(b0 + m) * NT + t + 1];
        xr[r] = Wxh[(size_t)xt * HID + cc] + bhv;
      }
      if (tid == 0) {
        const u32 target = 32u * (u32)(t + 1);
        while (__hip_atomic_load(myctr, __ATOMIC_ACQUIRE, __HIP_MEMORY_SCOPE_AGENT) < target) {
          __builtin_amdgcn_s_sleep(2);
        }
      }
    }
    __syncthreads();
  }
}

// ---------------------------------------------------------------------------
// gemm_go: per row r=(b,t):
//   half 0: out_pre[r][v] = fc_b[v] + Hs[r] . fc_w[v][0:1024]   -> d_out (f32)
//   half 1: G[r][v]       =           Hs[r] . fc_w[v][1024:2048] -> ws (bf16)
// ---------------------------------------------------------------------------
__global__ __launch_bounds__(256) void gemm_go(
    const u16* __restrict__ Hs, const float* __restrict__ fcw,
    const float* __restrict__ fcb, float* __restrict__ outpre,
    u16* __restrict__ G)
{
  const int row0 = blockIdx.x * 16;
  const int v2   = threadIdx.x & 63;
  const int rg   = threadIdx.x >> 6;
  __shared__ float Wc[64][129];

  for (int half = 0; half < 2; ++half) {
    float acc[4][2] = {};
    for (int kc = 0; kc < 16; ++kc) {
      __syncthreads();
      for (int jj = 0; jj < 32; ++jj) {
        int idx = threadIdx.x + jj * 256;   // 0..8191
        int k = idx & 63, v = idx >> 6;
        Wc[k][v] = fcw[(size_t)v * 2048 + half * 1024 + kc * 64 + k];
      }
      __syncthreads();
      #pragma unroll
      for (int r = 0; r < 4; ++r) {
        const u16* arow = Hs + (size_t)(row0 + rg * 4 + r) * HID + kc * 64;
        #pragma unroll
        for (int k8 = 0; k8 < 8; ++k8) {
          uint4 u = *reinterpret_cast<const uint4*>(arow + k8 * 8);
          u32 uu[4] = {u.x, u.y, u.z, u.w};
          #pragma unroll
          for (int p = 0; p < 4; ++p) {
            int k = k8 * 8 + p * 2;
            float a0 = bf2f((u16)(uu[p] & 0xffffu));
            float a1 = bf2f((u16)(uu[p] >> 16));
            acc[r][0] = fmaf(a0, Wc[k][v2],          acc[r][0]);
            acc[r][1] = fmaf(a0, Wc[k][v2 + 64],     acc[r][1]);
            acc[r][0] = fmaf(a1, Wc[k + 1][v2],      acc[r][0]);
            acc[r][1] = fmaf(a1, Wc[k + 1][v2 + 64], acc[r][1]);
          }
        }
      }
    }
    if (half == 0) {
      float b0 = fcb[v2], b1 = fcb[v2 + 64];
      #pragma unroll
      for (int r = 0; r < 4; ++r) {
        size_t orow = (size_t)(row0 + rg * 4 + r) * NV;
        outpre[orow + v2]      = acc[r][0] + b0;
        outpre[orow + v2 + 64] = acc[r][1] + b1;
      }
    } else {
      #pragma unroll
      for (int r = 0; r < 4; ++r) {
        size_t orow = (size_t)(row0 + rg * 4 + r) * NV;
        G[orow + v2]      = f2bf(acc[r][0]);
        G[orow + v2 + 64] = f2bf(acc[r][1]);
      }
    }
  }
}

// ---------------------------------------------------------------------------
// flash_attn: one wave per (b, 8 query rows). Online softmax over s,
// PV accumulated in the pre-projected 128-dim G space.
// 8 rows/wave: 128 fma per 16 B/lane loaded (2x the arithmetic intensity
// of the 4-row version), halves Hs re-stream traffic.
// ---------------------------------------------------------------------------
__global__ __launch_bounds__(64) void flash_attn(
    const u16* __restrict__ Hs, const u16* __restrict__ G,
    float* __restrict__ out)
{
  const int blk  = blockIdx.x;        // 128 batches * 64 row-octs
  const int b    = blk >> 6;
  const int t0   = (blk & 63) * 8;
  const int lane = threadIdx.x;
  const u16* __restrict__ Hb = Hs + (size_t)b * NT * HID;
  const u16* __restrict__ Gb = G  + (size_t)b * NT * NV;

  float q[8][16];
  #pragma unroll
  for (int r = 0; r < 8; ++r) {
    const u16* Hq = Hb + (size_t)(t0 + r) * HID;
    #pragma unroll
    for (int i = 0; i < 8; ++i) {
      u32 u = *reinterpret_cast<const u32*>(Hq + i * 128 + lane * 2);
      q[r][2 * i]     = bf2f((u16)(u & 0xffffu));
      q[r][2 * i + 1] = bf2f((u16)(u >> 16));
    }
  }

  float mx[8], l[8], a0[8], a1[8];
  #pragma unroll
  for (int r = 0; r < 8; ++r) { mx[r] = -INFINITY; l[r] = 0.f; a0[r] = 0.f; a1[r] = 0.f; }

  for (int s = 0; s < NT; ++s) {
    const u16* vrow = Hb + (size_t)s * HID;
    float p[8] = {0.f, 0.f, 0.f, 0.f, 0.f, 0.f, 0.f, 0.f};
    #pragma unroll
    for (int i = 0; i < 8; ++i) {
      u32 u = *reinterpret_cast<const u32*>(vrow + i * 128 + lane * 2);
      float v0 = bf2f((u16)(u & 0xffffu));
      float v1 = bf2f((u16)(u >> 16));
      #pragma unroll
      for (int r = 0; r < 8; ++r) {
        p[r] = fmaf(q[r][2 * i], v0, p[r]);
        p[r] = fmaf(q[r][2 * i + 1], v1, p[r]);
      }
    }
    #pragma unroll
    for (int off = 32; off >= 1; off >>= 1) {
      #pragma unroll
      for (int r = 0; r < 8; ++r) p[r] += __shfl_xor(p[r], off);
    }
    u32 g = *reinterpret_cast<const u32*>(Gb + s * NV + lane * 2);
    float ga  = bf2f((u16)(g & 0xffffu));
    float gb2 = bf2f((u16)(g >> 16));

    #pragma unroll
    for (int r = 0; r < 8; ++r) {
      float mn = fmaxf(mx[r], p[r]);
      float sc = __expf(mx[r] - mn);
      float e  = __expf(p[r] - mn);
      l[r] = l[r] * sc + e;
      mx[r] = mn;
      a0[r] = fmaf(e, ga,  a0[r] * sc);
      a1[r] = fmaf(e, gb2, a1[r] * sc);
    }
  }

  #pragma unroll
  for (int r = 0; r < 8; ++r) {
    float inv = 1.f / l[r];
    float2* po = reinterpret_cast<float2*>(out + ((size_t)b * NT + t0 + r) * NV) + lane;
    float2 o = *po;
    o.x += a0[r] * inv;
    o.y += a1[r] * inv;
    *po = o;
  }
}

// ---------------------------------------------------------------------------
// Workspace layout (~144.6 MiB):
//   Hs   bf16 [128][512][1024]  134,217,728 B
//   G    bf16 [128][512][128]    16,777,216 B
//   hbuf bf16 [2][128][1024]        524,288 B
//   ctr  u32  [8*64]                  2,048 B
// ---------------------------------------------------------------------------
extern "C" void kernel_launch(void* const* d_in, const int* in_sizes, int n_in,
                              void* d_out, int out_size, void* d_ws, size_t ws_size,
                              hipStream_t stream)
{
  const int*   x   = (const int*)  d_in[0];
  const float* Wxh = (const float*)d_in[1];
  const float* Whh = (const float*)d_in[2];
  const float* bh  = (const float*)d_in[3];
  const float* fcw = (const float*)d_in[4];
  const float* fcb = (const float*)d_in[5];
  float* out = (float*)d_out;

  u16* Hs   = (u16*)d_ws;
  u16* G    = Hs + (size_t)NB * NT * HID;
  u16* hbuf = G + (size_t)NB * NT * NV;
  u32* ctr  = (u32*)(hbuf + 2 * (size_t)NB * HID);

  // zero the per-bg barrier counters (ws is re-poisoned before every launch)
  hipMemsetAsync(ctr, 0, 8 * 64 * sizeof(u32), stream);

  // 1) persistent RNN: all 512 steps, one kernel
  rnn_persist<<<NBLK, 128, 0, stream>>>(x, Wxh, Whh, bh, Hs, hbuf, ctr);

  // 2) out_pre = Hs @ W1^T + fc_b (d_out, f32);  G = Hs @ W2^T (ws, bf16)
  gemm_go<<<dim3((NB * NT) / 16), 256, 0, stream>>>(Hs, fcw, fcb, out, G);

  // 3) flash attention in projected space: out += softmax(Hs Hs^T) @ G
  flash_attn<<<dim3(NB * (NT / 8)), 64, 0, stream>>>(Hs, G, out);
}

// Round 7
// 6544.691 us; speedup vs baseline: 1.5157x; 1.5157x over previous
//
#include <hip/hip_runtime.h>
#include <cmath>

#define HID 1024
#define NB  128   // batch
#define NT  512   // seq len
#define NV  128   // vocab
#define NBLK 256  // persistent RNN blocks: 8 bg x 32 cg

using u16 = unsigned short;
using u32 = unsigned int;

typedef __attribute__((ext_vector_type(8))) short s16x8;
typedef __attribute__((ext_vector_type(4))) float f32x4;

static __device__ __forceinline__ float bf2f(u16 u) {
  union { u32 i; float f; } v; v.i = ((u32)u) << 16; return v.f;
}
static __device__ __forceinline__ u16 f2bf(float f) {
  union { u32 i; float f; } v; v.f = f;
  u32 r = v.i + 0x7FFFu + ((v.i >> 16) & 1u);   // round-to-nearest-even
  return (u16)(r >> 16);
}

// ---------------------------------------------------------------------------
// Persistent RNN, all 512 steps, 256 blocks = 8 bg (16 batches) x 32 cg
// (32 cols). Whh col-slice in LDS (bf16, transposed, XOR-swizzled).
//
// Cross-block h exchange WITHOUT cache-maintenance ops (round-5 lesson:
// agent-scope acquire in a spin loop = buffer_inv per poll = ~11 us/step):
//   publish:  global_store_short ... sc0 sc1  (write-through to MALL)
//   order:    explicit s_waitcnt vmcnt(0), then RELAXED system-scope
//             atomicAdd on a per-bg counter (MALL-side, no wbl2)
//   poll:     RELAXED system-scope atomic load (no buffer_inv)
//   consume:  global_load_dwordx4 ... sc0 sc1 (bypass stale L1/L2 — the
//             double buffer recycles addresses every 2 steps) into
//             XOR-swizzled LDS stage, then ds_read for MFMA A-fragments.
// L2 is never invalidated -> Wxh/x/xe prefetches stay L2-hot.
// NOTE: all 16 asm outputs are EARLY-CLOBBER (=&v) — round-6 crash was the
// allocator overlapping the address pair with s[0] (outputs written before
// the last input read in a multi-instruction asm block).
// ---------------------------------------------------------------------------
__global__ __launch_bounds__(128, 1) void rnn_persist(
    const int* __restrict__ x, const float* __restrict__ Wxh,
    const float* __restrict__ Whh, const float* __restrict__ bh,
    u16* __restrict__ Hs, u16* __restrict__ hbuf, u32* __restrict__ ctr)
{
  const int blk  = blockIdx.x;
  const int bg   = blk & 7;
  const int cg   = blk >> 3;
  const int tid  = threadIdx.x;     // 0..127 (2 waves)
  const int wave = tid >> 6;
  const int lane = tid & 63;
  const int b0   = bg * 16;
  const int c0   = cg * 32;

  __shared__ u16 Wt[32 * 1024];                 // B operand, XOR-swizzled
  __shared__ __align__(16) u16 hstage[16 * 1024]; // A operand, XOR-swizzled

  // ---- stage Wt (transpose Whh[k][c0+col] -> Wt[col][k], bf16, swizzle) ----
  for (int it = 0; it < 128; ++it) {
    int idx = tid + it * 128;       // 0..16383
    int col = idx & 31;
    int k   = (idx >> 5) * 2;       // k pair
    float w0 = Whh[(size_t)k * HID + c0 + col];
    float w1 = Whh[(size_t)(k + 1) * HID + c0 + col];
    u32 pk = ((u32)f2bf(w1) << 16) | (u32)f2bf(w0);
    u32 byteo = ((u32)col * 2048 + (u32)k * 2) ^ ((u32)(col & 7) << 4);
    *reinterpret_cast<u32*>(reinterpret_cast<char*>(Wt) + byteo) = pk;
  }

  // MFMA fragment geometry (16x16x32 bf16):
  //   A: row = lane&15 (batch m), k-slice = (lane>>4)*8
  //   B: col = lane&15 (out col n), k-slice = (lane>>4)*8
  //   C: n = lane&15, m = (lane>>4)*4 + reg
  const int frow = lane & 15;
  const int koff = (lane >> 4) * 8;
  const int col  = wave * 16 + (lane & 15);
  const int cc   = c0 + col;
  const u32 swz   = (u32)(col & 7) << 4;
  const u32 bbase = (u32)col * 2048 + (u32)koff * 2;
  const char* wtb = reinterpret_cast<const char*>(Wt);
  const char* hsb = reinterpret_cast<const char*>(hstage);
  const u32 abase = (u32)frow * 2048 + (u32)koff * 2;
  const u32 axor  = (u32)(frow & 7) << 4;

  // stage-write mapping: thread owns 256 B of the 32 KB h slice (one row)
  const u32 sbase = (u32)tid * 256;
  const u32 sxor  = (u32)((tid >> 3) & 7) << 4;

  const float bhv = bh[cc];
  float xr[4];
  #pragma unroll
  for (int r = 0; r < 4; ++r) {
    int m = (lane >> 4) * 4 + r;
    int xt = x[(size_t)(b0 + m) * NT];
    xr[r] = Wxh[(size_t)xt * HID + cc] + bhv;
  }
  __syncthreads();                  // Wt ready

  u32* __restrict__ myctr = ctr + bg * 64;   // 256 B apart per bg

  for (int t = 0; t < NT; ++t) {
    // ---- stage h_prev into LDS via coherent (MALL-bypass) loads ----
    if (t > 0) {
      const char* src = reinterpret_cast<const char*>(
          hbuf + (size_t)(t & 1) * NB * HID + (size_t)b0 * HID) + sbase;
      uint4 s[16];
      asm volatile(
        "global_load_dwordx4 %0, %16, off sc0 sc1\n\t"
        "global_load_dwordx4 %1, %16, off offset:16 sc0 sc1\n\t"
        "global_load_dwordx4 %2, %16, off offset:32 sc0 sc1\n\t"
        "global_load_dwordx4 %3, %16, off offset:48 sc0 sc1\n\t"
        "global_load_dwordx4 %4, %16, off offset:64 sc0 sc1\n\t"
        "global_load_dwordx4 %5, %16, off offset:80 sc0 sc1\n\t"
        "global_load_dwordx4 %6, %16, off offset:96 sc0 sc1\n\t"
        "global_load_dwordx4 %7, %16, off offset:112 sc0 sc1\n\t"
        "global_load_dwordx4 %8, %16, off offset:128 sc0 sc1\n\t"
        "global_load_dwordx4 %9, %16, off offset:144 sc0 sc1\n\t"
        "global_load_dwordx4 %10, %16, off offset:160 sc0 sc1\n\t"
        "global_load_dwordx4 %11, %16, off offset:176 sc0 sc1\n\t"
        "global_load_dwordx4 %12, %16, off offset:192 sc0 sc1\n\t"
        "global_load_dwordx4 %13, %16, off offset:208 sc0 sc1\n\t"
        "global_load_dwordx4 %14, %16, off offset:224 sc0 sc1\n\t"
        "global_load_dwordx4 %15, %16, off offset:240 sc0 sc1\n\t"
        "s_waitcnt vmcnt(0)"
        : "=&v"(s[0]), "=&v"(s[1]), "=&v"(s[2]), "=&v"(s[3]),
          "=&v"(s[4]), "=&v"(s[5]), "=&v"(s[6]), "=&v"(s[7]),
          "=&v"(s[8]), "=&v"(s[9]), "=&v"(s[10]), "=&v"(s[11]),
          "=&v"(s[12]), "=&v"(s[13]), "=&v"(s[14]), "=&v"(s[15])
        : "v"(src) : "memory");
      __builtin_amdgcn_sched_barrier(0);
      char* dst = reinterpret_cast<char*>(hstage);
      #pragma unroll
      for (int i = 0; i < 16; ++i)
        *reinterpret_cast<uint4*>(dst + ((sbase + (u32)i * 16) ^ sxor)) = s[i];
    }
    __syncthreads();   // hstage ready

    // ---- S = h_prev @ Wslice via MFMA (K = 1024 = 32 chunks) ----
    f32x4 acc = {0.f, 0.f, 0.f, 0.f};
    if (t > 0) {
      #pragma unroll 8
      for (int kc = 0; kc < 32; ++kc) {
        s16x8 af = *reinterpret_cast<const s16x8*>(hsb + ((abase + (u32)kc * 64) ^ axor));
        s16x8 bf = *reinterpret_cast<const s16x8*>(wtb + ((bbase + (u32)kc * 64) ^ swz));
        acc = __builtin_amdgcn_mfma_f32_16x16x32_bf16(af, bf, acc, 0, 0, 0);
      }
    }

    // ---- epilogue: tanh, publish h_t write-through to MALL ----
    u16* hnext = hbuf + (size_t)((t + 1) & 1) * NB * HID;
    u16 hb[4];
    #pragma unroll
    for (int r = 0; r < 4; ++r) {
      int m = (lane >> 4) * 4 + r;
      float h = tanhf(acc[r] + xr[r]);
      hb[r] = f2bf(h);
      u16* pa = hnext + (size_t)(b0 + m) * HID + cc;
      asm volatile("global_store_short %0, %1, off sc0 sc1"
                   :: "v"(pa), "v"((u32)hb[r]) : "memory");
    }
    asm volatile("s_waitcnt vmcnt(0)" ::: "memory");  // publish at MALL
    __syncthreads();

    if (tid == 0 && t < NT - 1)
      __hip_atomic_fetch_add(myctr, 1u, __ATOMIC_RELAXED, __HIP_MEMORY_SCOPE_SYSTEM);

    // ---- overlap the spin: archive Hs + prefetch next xe (L2-hot now) ----
    #pragma unroll
    for (int r = 0; r < 4; ++r) {
      int m = (lane >> 4) * 4 + r;
      Hs[((size_t)(b0 + m) * NT + t) * HID + cc] = hb[r];
    }
    if (t < NT - 1) {
      #pragma unroll
      for (int r = 0; r < 4; ++r) {
        int m = (lane >> 4) * 4 + r;
        int xt = x[(size_t)(b0 + m) * NT + t + 1];
        xr[r] = Wxh[(size_t)xt * HID + cc] + bhv;
      }
      if (tid == 0) {
        const u32 target = 32u * (u32)(t + 1);
        while (__hip_atomic_load(myctr, __ATOMIC_RELAXED, __HIP_MEMORY_SCOPE_SYSTEM) < target)
          __builtin_amdgcn_s_sleep(1);
      }
    }
    __syncthreads();
  }
}

// ---------------------------------------------------------------------------
// gemm_go: per row r=(b,t):
//   half 0: out_pre[r][v] = fc_b[v] + Hs[r] . fc_w[v][0:1024]   -> d_out (f32)
//   half 1: G[r][v]       =           Hs[r] . fc_w[v][1024:2048] -> ws (bf16)
// ---------------------------------------------------------------------------
__global__ __launch_bounds__(256) void gemm_go(
    const u16* __restrict__ Hs, const float* __restrict__ fcw,
    const float* __restrict__ fcb, float* __restrict__ outpre,
    u16* __restrict__ G)
{
  const int row0 = blockIdx.x * 16;
  const int v2   = threadIdx.x & 63;
  const int rg   = threadIdx.x >> 6;
  __shared__ float Wc[64][129];

  for (int half = 0; half < 2; ++half) {
    float acc[4][2] = {};
    for (int kc = 0; kc < 16; ++kc) {
      __syncthreads();
      for (int jj = 0; jj < 32; ++jj) {
        int idx = threadIdx.x + jj * 256;   // 0..8191
        int k = idx & 63, v = idx >> 6;
        Wc[k][v] = fcw[(size_t)v * 2048 + half * 1024 + kc * 64 + k];
      }
      __syncthreads();
      #pragma unroll
      for (int r = 0; r < 4; ++r) {
        const u16* arow = Hs + (size_t)(row0 + rg * 4 + r) * HID + kc * 64;
        #pragma unroll
        for (int k8 = 0; k8 < 8; ++k8) {
          uint4 u = *reinterpret_cast<const uint4*>(arow + k8 * 8);
          u32 uu[4] = {u.x, u.y, u.z, u.w};
          #pragma unroll
          for (int p = 0; p < 4; ++p) {
            int k = k8 * 8 + p * 2;
            float a0 = bf2f((u16)(uu[p] & 0xffffu));
            float a1 = bf2f((u16)(uu[p] >> 16));
            acc[r][0] = fmaf(a0, Wc[k][v2],          acc[r][0]);
            acc[r][1] = fmaf(a0, Wc[k][v2 + 64],     acc[r][1]);
            acc[r][0] = fmaf(a1, Wc[k + 1][v2],      acc[r][0]);
            acc[r][1] = fmaf(a1, Wc[k + 1][v2 + 64], acc[r][1]);
          }
        }
      }
    }
    if (half == 0) {
      float b0 = fcb[v2], b1 = fcb[v2 + 64];
      #pragma unroll
      for (int r = 0; r < 4; ++r) {
        size_t orow = (size_t)(row0 + rg * 4 + r) * NV;
        outpre[orow + v2]      = acc[r][0] + b0;
        outpre[orow + v2 + 64] = acc[r][1] + b1;
      }
    } else {
      #pragma unroll
      for (int r = 0; r < 4; ++r) {
        size_t orow = (size_t)(row0 + rg * 4 + r) * NV;
        G[orow + v2]      = f2bf(acc[r][0]);
        G[orow + v2 + 64] = f2bf(acc[r][1]);
      }
    }
  }
}

// ---------------------------------------------------------------------------
// flash_attn: one wave per (b, 8 query rows). Online softmax over s,
// PV accumulated in the pre-projected 128-dim G space.
// ---------------------------------------------------------------------------
__global__ __launch_bounds__(64) void flash_attn(
    const u16* __restrict__ Hs, const u16* __restrict__ G,
    float* __restrict__ out)
{
  const int blk  = blockIdx.x;        // 128 batches * 64 row-octs
  const int b    = blk >> 6;
  const int t0   = (blk & 63) * 8;
  const int lane = threadIdx.x;
  const u16* __restrict__ Hb = Hs + (size_t)b * NT * HID;
  const u16* __restrict__ Gb = G  + (size_t)b * NT * NV;

  float q[8][16];
  #pragma unroll
  for (int r = 0; r < 8; ++r) {
    const u16* Hq = Hb + (size_t)(t0 + r) * HID;
    #pragma unroll
    for (int i = 0; i < 8; ++i) {
      u32 u = *reinterpret_cast<const u32*>(Hq + i * 128 + lane * 2);
      q[r][2 * i]     = bf2f((u16)(u & 0xffffu));
      q[r][2 * i + 1] = bf2f((u16)(u >> 16));
    }
  }

  float mx[8], l[8], a0[8], a1[8];
  #pragma unroll
  for (int r = 0; r < 8; ++r) { mx[r] = -INFINITY; l[r] = 0.f; a0[r] = 0.f; a1[r] = 0.f; }

  for (int s = 0; s < NT; ++s) {
    const u16* vrow = Hb + (size_t)s * HID;
    float p[8] = {0.f, 0.f, 0.f, 0.f, 0.f, 0.f, 0.f, 0.f};
    #pragma unroll
    for (int i = 0; i < 8; ++i) {
      u32 u = *reinterpret_cast<const u32*>(vrow + i * 128 + lane * 2);
      float v0 = bf2f((u16)(u & 0xffffu));
      float v1 = bf2f((u16)(u >> 16));
      #pragma unroll
      for (int r = 0; r < 8; ++r) {
        p[r] = fmaf(q[r][2 * i], v0, p[r]);
        p[r] = fmaf(q[r][2 * i + 1], v1, p[r]);
      }
    }
    #pragma unroll
    for (int off = 32; off >= 1; off >>= 1) {
      #pragma unroll
      for (int r = 0; r < 8; ++r) p[r] += __shfl_xor(p[r], off);
    }
    u32 g = *reinterpret_cast<const u32*>(Gb + s * NV + lane * 2);
    float ga  = bf2f((u16)(g & 0xffffu));
    float gb2 = bf2f((u16)(g >> 16));

    #pragma unroll
    for (int r = 0; r < 8; ++r) {
      float mn = fmaxf(mx[r], p[r]);
      float sc = __expf(mx[r] - mn);
      float e  = __expf(p[r] - mn);
      l[r] = l[r] * sc + e;
      mx[r] = mn;
      a0[r] = fmaf(e, ga,  a0[r] * sc);
      a1[r] = fmaf(e, gb2, a1[r] * sc);
    }
  }

  #pragma unroll
  for (int r = 0; r < 8; ++r) {
    float inv = 1.f / l[r];
    float2* po = reinterpret_cast<float2*>(out + ((size_t)b * NT + t0 + r) * NV) + lane;
    float2 o = *po;
    o.x += a0[r] * inv;
    o.y += a1[r] * inv;
    *po = o;
  }
}

// ---------------------------------------------------------------------------
// Workspace layout (~144.6 MiB):
//   Hs   bf16 [128][512][1024]  134,217,728 B
//   G    bf16 [128][512][128]    16,777,216 B
//   hbuf bf16 [2][128][1024]        524,288 B
//   ctr  u32  [8*64]                  2,048 B
// ---------------------------------------------------------------------------
extern "C" void kernel_launch(void* const* d_in, const int* in_sizes, int n_in,
                              void* d_out, int out_size, void* d_ws, size_t ws_size,
                              hipStream_t stream)
{
  const int*   x   = (const int*)  d_in[0];
  const float* Wxh = (const float*)d_in[1];
  const float* Whh = (const float*)d_in[2];
  const float* bh  = (const float*)d_in[3];
  const float* fcw = (const float*)d_in[4];
  const float* fcb = (const float*)d_in[5];
  float* out = (float*)d_out;

  u16* Hs   = (u16*)d_ws;
  u16* G    = Hs + (size_t)NB * NT * HID;
  u16* hbuf = G + (size_t)NB * NT * NV;
  u32* ctr  = (u32*)(hbuf + 2 * (size_t)NB * HID);

  // zero the per-bg barrier counters (ws is re-poisoned before every launch)
  hipMemsetAsync(ctr, 0, 8 * 64 * sizeof(u32), stream);

  // 1) persistent RNN: all 512 steps, one kernel
  rnn_persist<<<NBLK, 128, 0, stream>>>(x, Wxh, Whh, bh, Hs, hbuf, ctr);

  // 2) out_pre = Hs @ W1^T + fc_b (d_out, f32);  G = Hs @ W2^T (ws, bf16)
  gemm_go<<<dim3((NB * NT) / 16), 256, 0, stream>>>(Hs, fcw, fcb, out, G);

  // 3) flash attention in projected space: out += softmax(Hs Hs^T) @ G
  flash_attn<<<dim3(NB * (NT / 8)), 64, 0, stream>>>(Hs, G, out);
}

// Round 8
// 3556.026 us; speedup vs baseline: 2.7895x; 1.8405x over previous
//
#include <hip/hip_runtime.h>
#include <cmath>

#define HID 1024
#define NB  128   // batch
#define NT  512   // seq len
#define NV  128   // vocab
#define NBLK 256  // persistent RNN blocks: 8 bg x 32 cg

using u16 = unsigned short;
using u32 = unsigned int;

typedef __attribute__((ext_vector_type(8))) short s16x8;
typedef __attribute__((ext_vector_type(4))) float f32x4;

static __device__ __forceinline__ float bf2f(u16 u) {
  union { u32 i; float f; } v; v.i = ((u32)u) << 16; return v.f;
}
static __device__ __forceinline__ u16 f2bf(float f) {
  union { u32 i; float f; } v; v.f = f;
  u32 r = v.i + 0x7FFFu + ((v.i >> 16) & 1u);   // round-to-nearest-even
  return (u16)(r >> 16);
}

// ---------------------------------------------------------------------------
// Persistent RNN (UNCHANGED from the passing round-7 kernel).
// MALL-coherent h exchange: sc0 sc1 write-through stores + relaxed
// system-scope counter + sc0 sc1 bypass loads into swizzled LDS.
// ---------------------------------------------------------------------------
__global__ __launch_bounds__(128, 1) void rnn_persist(
    const int* __restrict__ x, const float* __restrict__ Wxh,
    const float* __restrict__ Whh, const float* __restrict__ bh,
    u16* __restrict__ Hs, u16* __restrict__ hbuf, u32* __restrict__ ctr)
{
  const int blk  = blockIdx.x;
  const int bg   = blk & 7;
  const int cg   = blk >> 3;
  const int tid  = threadIdx.x;     // 0..127 (2 waves)
  const int wave = tid >> 6;
  const int lane = tid & 63;
  const int b0   = bg * 16;
  const int c0   = cg * 32;

  __shared__ u16 Wt[32 * 1024];                 // B operand, XOR-swizzled
  __shared__ __align__(16) u16 hstage[16 * 1024]; // A operand, XOR-swizzled

  for (int it = 0; it < 128; ++it) {
    int idx = tid + it * 128;       // 0..16383
    int col = idx & 31;
    int k   = (idx >> 5) * 2;       // k pair
    float w0 = Whh[(size_t)k * HID + c0 + col];
    float w1 = Whh[(size_t)(k + 1) * HID + c0 + col];
    u32 pk = ((u32)f2bf(w1) << 16) | (u32)f2bf(w0);
    u32 byteo = ((u32)col * 2048 + (u32)k * 2) ^ ((u32)(col & 7) << 4);
    *reinterpret_cast<u32*>(reinterpret_cast<char*>(Wt) + byteo) = pk;
  }

  const int frow = lane & 15;
  const int koff = (lane >> 4) * 8;
  const int col  = wave * 16 + (lane & 15);
  const int cc   = c0 + col;
  const u32 swz   = (u32)(col & 7) << 4;
  const u32 bbase = (u32)col * 2048 + (u32)koff * 2;
  const char* wtb = reinterpret_cast<const char*>(Wt);
  const char* hsb = reinterpret_cast<const char*>(hstage);
  const u32 abase = (u32)frow * 2048 + (u32)koff * 2;
  const u32 axor  = (u32)(frow & 7) << 4;

  const u32 sbase = (u32)tid * 256;
  const u32 sxor  = (u32)((tid >> 3) & 7) << 4;

  const float bhv = bh[cc];
  float xr[4];
  #pragma unroll
  for (int r = 0; r < 4; ++r) {
    int m = (lane >> 4) * 4 + r;
    int xt = x[(size_t)(b0 + m) * NT];
    xr[r] = Wxh[(size_t)xt * HID + cc] + bhv;
  }
  __syncthreads();                  // Wt ready

  u32* __restrict__ myctr = ctr + bg * 64;   // 256 B apart per bg

  for (int t = 0; t < NT; ++t) {
    if (t > 0) {
      const char* src = reinterpret_cast<const char*>(
          hbuf + (size_t)(t & 1) * NB * HID + (size_t)b0 * HID) + sbase;
      uint4 s[16];
      asm volatile(
        "global_load_dwordx4 %0, %16, off sc0 sc1\n\t"
        "global_load_dwordx4 %1, %16, off offset:16 sc0 sc1\n\t"
        "global_load_dwordx4 %2, %16, off offset:32 sc0 sc1\n\t"
        "global_load_dwordx4 %3, %16, off offset:48 sc0 sc1\n\t"
        "global_load_dwordx4 %4, %16, off offset:64 sc0 sc1\n\t"
        "global_load_dwordx4 %5, %16, off offset:80 sc0 sc1\n\t"
        "global_load_dwordx4 %6, %16, off offset:96 sc0 sc1\n\t"
        "global_load_dwordx4 %7, %16, off offset:112 sc0 sc1\n\t"
        "global_load_dwordx4 %8, %16, off offset:128 sc0 sc1\n\t"
        "global_load_dwordx4 %9, %16, off offset:144 sc0 sc1\n\t"
        "global_load_dwordx4 %10, %16, off offset:160 sc0 sc1\n\t"
        "global_load_dwordx4 %11, %16, off offset:176 sc0 sc1\n\t"
        "global_load_dwordx4 %12, %16, off offset:192 sc0 sc1\n\t"
        "global_load_dwordx4 %13, %16, off offset:208 sc0 sc1\n\t"
        "global_load_dwordx4 %14, %16, off offset:224 sc0 sc1\n\t"
        "global_load_dwordx4 %15, %16, off offset:240 sc0 sc1\n\t"
        "s_waitcnt vmcnt(0)"
        : "=&v"(s[0]), "=&v"(s[1]), "=&v"(s[2]), "=&v"(s[3]),
          "=&v"(s[4]), "=&v"(s[5]), "=&v"(s[6]), "=&v"(s[7]),
          "=&v"(s[8]), "=&v"(s[9]), "=&v"(s[10]), "=&v"(s[11]),
          "=&v"(s[12]), "=&v"(s[13]), "=&v"(s[14]), "=&v"(s[15])
        : "v"(src) : "memory");
      __builtin_amdgcn_sched_barrier(0);
      char* dst = reinterpret_cast<char*>(hstage);
      #pragma unroll
      for (int i = 0; i < 16; ++i)
        *reinterpret_cast<uint4*>(dst + ((sbase + (u32)i * 16) ^ sxor)) = s[i];
    }
    __syncthreads();   // hstage ready

    f32x4 acc = {0.f, 0.f, 0.f, 0.f};
    if (t > 0) {
      #pragma unroll 8
      for (int kc = 0; kc < 32; ++kc) {
        s16x8 af = *reinterpret_cast<const s16x8*>(hsb + ((abase + (u32)kc * 64) ^ axor));
        s16x8 bf = *reinterpret_cast<const s16x8*>(wtb + ((bbase + (u32)kc * 64) ^ swz));
        acc = __builtin_amdgcn_mfma_f32_16x16x32_bf16(af, bf, acc, 0, 0, 0);
      }
    }

    u16* hnext = hbuf + (size_t)((t + 1) & 1) * NB * HID;
    u16 hb[4];
    #pragma unroll
    for (int r = 0; r < 4; ++r) {
      int m = (lane >> 4) * 4 + r;
      float h = tanhf(acc[r] + xr[r]);
      hb[r] = f2bf(h);
      u16* pa = hnext + (size_t)(b0 + m) * HID + cc;
      asm volatile("global_store_short %0, %1, off sc0 sc1"
                   :: "v"(pa), "v"((u32)hb[r]) : "memory");
    }
    asm volatile("s_waitcnt vmcnt(0)" ::: "memory");  // publish at MALL
    __syncthreads();

    if (tid == 0 && t < NT - 1)
      __hip_atomic_fetch_add(myctr, 1u, __ATOMIC_RELAXED, __HIP_MEMORY_SCOPE_SYSTEM);

    #pragma unroll
    for (int r = 0; r < 4; ++r) {
      int m = (lane >> 4) * 4 + r;
      Hs[((size_t)(b0 + m) * NT + t) * HID + cc] = hb[r];
    }
    if (t < NT - 1) {
      #pragma unroll
      for (int r = 0; r < 4; ++r) {
        int m = (lane >> 4) * 4 + r;
        int xt = x[(size_t)(b0 + m) * NT + t + 1];
        xr[r] = Wxh[(size_t)xt * HID + cc] + bhv;
      }
      if (tid == 0) {
        const u32 target = 32u * (u32)(t + 1);
        while (__hip_atomic_load(myctr, __ATOMIC_RELAXED, __HIP_MEMORY_SCOPE_SYSTEM) < target)
          __builtin_amdgcn_s_sleep(1);
      }
    }
    __syncthreads();
  }
}

// ---------------------------------------------------------------------------
// fcw_cvt: fc_w f32 [128][2048] -> bf16 copy (into the retired hbuf region).
// ---------------------------------------------------------------------------
__global__ __launch_bounds__(256) void fcw_cvt(
    const float* __restrict__ fcw, u16* __restrict__ fcwb)
{
  int i = (blockIdx.x * 256 + threadIdx.x) * 4;   // 262144 elems / 4
  float4 f = *reinterpret_cast<const float4*>(fcw + i);
  uint2 o;
  o.x = (u32)f2bf(f.x) | ((u32)f2bf(f.y) << 16);
  o.y = (u32)f2bf(f.z) | ((u32)f2bf(f.w) << 16);
  *reinterpret_cast<uint2*>(fcwb + i) = o;
}

// ---------------------------------------------------------------------------
// gemm_go_mfma: rows = (b,t); both halves share A = Hs row (k=0..1023):
//   n<8 : outpre[row][n*16+c] = Hs[row] . fcw[v=n*16+c][0:1024]   + fcb
//   n>=8: G[row][(n-8)*16+c]  = Hs[row] . fcw[v][1024:2048]  (bf16)
// Block 256 = 4 waves x 16 rows = 64 rows/block; B-frags direct from the
// L2-resident bf16 fcwb (512 KB); MFMA 16x16x32, validated fragment layouts.
// ---------------------------------------------------------------------------
__global__ __launch_bounds__(256) void gemm_go_mfma(
    const u16* __restrict__ Hs, const u16* __restrict__ fcwb,
    const float* __restrict__ fcb, float* __restrict__ outpre,
    u16* __restrict__ G)
{
  const int row0 = blockIdx.x * 64;
  const int w    = threadIdx.x >> 6;
  const int lane = threadIdx.x & 63;
  const int frow = lane & 15;
  const int koff = (lane >> 4) * 8;
  const int g4   = lane >> 4;

  f32x4 acc[16] = {};
  const u16* ap0 = Hs + (size_t)(row0 + w * 16 + frow) * HID + koff;

  for (int kc = 0; kc < 32; ++kc) {
    s16x8 a = *reinterpret_cast<const s16x8*>(ap0 + kc * 32);
    #pragma unroll
    for (int n = 0; n < 16; ++n) {
      int v = (n & 7) * 16 + frow;
      int kb = (n >> 3) * 1024 + kc * 32 + koff;
      s16x8 bf = *reinterpret_cast<const s16x8*>(fcwb + (size_t)v * 2048 + kb);
      acc[n] = __builtin_amdgcn_mfma_f32_16x16x32_bf16(a, bf, acc[n], 0, 0, 0);
    }
  }

  #pragma unroll
  for (int n = 0; n < 16; ++n) {
    int v = (n & 7) * 16 + frow;
    float fb = (n < 8) ? fcb[v] : 0.f;
    #pragma unroll
    for (int r = 0; r < 4; ++r) {
      size_t row = (size_t)(row0 + w * 16 + g4 * 4 + r);
      if (n < 8) outpre[row * NV + v] = acc[n][r] + fb;
      else       G[row * NV + v]      = f2bf(acc[n][r]);
    }
  }
}

// ---------------------------------------------------------------------------
// attn_mfma: block = (b, 64 q-rows), 4 waves x 16 rows. Per 64-s-tile:
//   QK^T: K-chunks [64s x 128k] staged in swizzled LDS (shared), Q A-frags
//         direct from L2-hot Hs; S accum f32 (16x16x32 MFMA).
//   online softmax in C-layout (row q=(lane>>4)*4+r, col s=lane&15+16*st2),
//   16-lane shfl_xor row-reduce.
//   PV in projected G space: P -> swizzled per-wave LDS tile -> A-frags;
//   B-frags from transposed Gt[v][s] LDS tile. O accum [16q x 128v]/wave.
// out += P V / l  (on top of gemm's out_pre).
// ---------------------------------------------------------------------------
__global__ __launch_bounds__(256) void attn_mfma(
    const u16* __restrict__ Hs, const u16* __restrict__ G,
    float* __restrict__ out)
{
  const int blk  = blockIdx.x;        // 128 b x 8 q-tiles
  const int b    = blk >> 3;
  const int q0   = (blk & 7) * 64;
  const int tid  = threadIdx.x;
  const int w    = tid >> 6;
  const int lane = tid & 63;
  const int frow = lane & 15;
  const int koff = (lane >> 4) * 8;
  const int g4   = lane >> 4;

  __shared__ __align__(16) u16 Kc[64 * 128];   // 16 KB, swizzled
  __shared__ __align__(16) u16 Gt[128 * 64];   // 16 KB, swizzled (v-major)
  __shared__ __align__(16) u16 Pl[64 * 64];    // 8 KB, swizzled

  const u16* __restrict__ Hb = Hs + (size_t)b * NT * HID;
  const u16* __restrict__ Gb = G  + (size_t)b * NT * NV;
  const char* kcb = reinterpret_cast<const char*>(Kc);
  const char* gtb = reinterpret_cast<const char*>(Gt);
  const char* plb = reinterpret_cast<const char*>(Pl);

  float m[4], l[4];
  #pragma unroll
  for (int r = 0; r < 4; ++r) { m[r] = -INFINITY; l[r] = 0.f; }
  f32x4 accO[8] = {};

  for (int st = 0; st < 8; ++st) {
    const int s0 = st * 64;
    __syncthreads();                       // prev tile's Gt/Pl consumers done

    // ---- stage Gt[v][s] (transposed G tile) ----
    for (int it = 0; it < 32; ++it) {
      int idx = tid + it * 256;            // 0..8191
      int s = idx >> 7, v = idx & 127;
      u16 gv = Gb[(size_t)(s0 + s) * NV + v];
      *reinterpret_cast<u16*>(const_cast<char*>(gtb) +
          (((u32)v * 128 + (u32)s * 2) ^ ((u32)(v & 7) << 4))) = gv;
    }

    // ---- S = Q K^T accumulation over k-chunks of 128 ----
    f32x4 sacc[4] = {};
    for (int kc = 0; kc < 8; ++kc) {
      __syncthreads();                     // prev Kc consumed
      #pragma unroll
      for (int i = 0; i < 4; ++i) {
        int idx = tid + i * 256;           // 0..1023
        int row = idx >> 4, cg = idx & 15;
        uint4 kd = *reinterpret_cast<const uint4*>(
            Hb + (size_t)(s0 + row) * HID + kc * 128 + cg * 8);
        *reinterpret_cast<uint4*>(const_cast<char*>(kcb) +
            (((u32)row * 256 + (u32)cg * 16) ^ ((u32)(row & 7) << 4))) = kd;
      }
      __syncthreads();

      s16x8 aq[4];
      const u16* qp = Hb + (size_t)(q0 + w * 16 + frow) * HID + kc * 128 + koff;
      #pragma unroll
      for (int ks = 0; ks < 4; ++ks)
        aq[ks] = *reinterpret_cast<const s16x8*>(qp + ks * 32);

      #pragma unroll
      for (int ks = 0; ks < 4; ++ks) {
        #pragma unroll
        for (int n = 0; n < 4; ++n) {
          int srow = n * 16 + frow;
          s16x8 bk = *reinterpret_cast<const s16x8*>(kcb +
              (((u32)srow * 256 + (u32)(ks * 32 + koff) * 2) ^ ((u32)(srow & 7) << 4)));
          sacc[n] = __builtin_amdgcn_mfma_f32_16x16x32_bf16(aq[ks], bk, sacc[n], 0, 0, 0);
        }
      }
    }

    // ---- online softmax (rows replicated across each 16-lane group) ----
    float p[4][4];
    float sc[4];
    #pragma unroll
    for (int r = 0; r < 4; ++r) {
      float t = fmaxf(fmaxf(sacc[0][r], sacc[1][r]), fmaxf(sacc[2][r], sacc[3][r]));
      t = fmaxf(t, __shfl_xor(t, 1));
      t = fmaxf(t, __shfl_xor(t, 2));
      t = fmaxf(t, __shfl_xor(t, 4));
      t = fmaxf(t, __shfl_xor(t, 8));
      float mn = fmaxf(m[r], t);
      sc[r] = __expf(m[r] - mn);
      float rs = 0.f;
      #pragma unroll
      for (int n = 0; n < 4; ++n) { p[n][r] = __expf(sacc[n][r] - mn); rs += p[n][r]; }
      rs += __shfl_xor(rs, 1);
      rs += __shfl_xor(rs, 2);
      rs += __shfl_xor(rs, 4);
      rs += __shfl_xor(rs, 8);
      l[r] = l[r] * sc[r] + rs;
      m[r] = mn;
    }
    #pragma unroll
    for (int v8 = 0; v8 < 8; ++v8)
      #pragma unroll
      for (int r = 0; r < 4; ++r) accO[v8][r] *= sc[r];

    // ---- P -> per-wave LDS tile (bf16, swizzled) ----
    #pragma unroll
    for (int n = 0; n < 4; ++n) {
      int s = n * 16 + frow;
      #pragma unroll
      for (int r = 0; r < 4; ++r) {
        int q = w * 16 + g4 * 4 + r;
        *reinterpret_cast<u16*>(const_cast<char*>(plb) +
            (((u32)q * 128 + (u32)s * 2) ^ ((u32)(q & 7) << 4))) = f2bf(p[n][r]);
      }
    }
    asm volatile("s_waitcnt lgkmcnt(0)" ::: "memory");   // own-wave P writes done
    __builtin_amdgcn_sched_barrier(0);

    // ---- PV: O += P . Gt  (per-wave P region; Gt staged before kc barriers)
    #pragma unroll
    for (int ss = 0; ss < 2; ++ss) {
      int qrow = w * 16 + frow;
      s16x8 ap = *reinterpret_cast<const s16x8*>(plb +
          (((u32)qrow * 128 + (u32)(ss * 32 + koff) * 2) ^ ((u32)(qrow & 7) << 4)));
      #pragma unroll
      for (int v8 = 0; v8 < 8; ++v8) {
        int vrow = v8 * 16 + frow;
        s16x8 bg = *reinterpret_cast<const s16x8*>(gtb +
            (((u32)vrow * 128 + (u32)(ss * 32 + koff) * 2) ^ ((u32)(vrow & 7) << 4)));
        accO[v8] = __builtin_amdgcn_mfma_f32_16x16x32_bf16(ap, bg, accO[v8], 0, 0, 0);
      }
    }
  }

  // ---- epilogue: out += accO / l ----
  float inv[4];
  #pragma unroll
  for (int r = 0; r < 4; ++r) inv[r] = 1.f / l[r];
  #pragma unroll
  for (int v8 = 0; v8 < 8; ++v8) {
    int c = v8 * 16 + frow;
    #pragma unroll
    for (int r = 0; r < 4; ++r) {
      size_t row = (size_t)b * NT + q0 + w * 16 + g4 * 4 + r;
      out[row * NV + c] += accO[v8][r] * inv[r];
    }
  }
}

// ---------------------------------------------------------------------------
// Workspace layout (~144.6 MiB, unchanged):
//   Hs   bf16 [128][512][1024]  134,217,728 B
//   G    bf16 [128][512][128]    16,777,216 B
//   hbuf bf16 [2][128][1024]        524,288 B   (reused as fcwb after RNN)
//   ctr  u32  [8*64]                  2,048 B
// ---------------------------------------------------------------------------
extern "C" void kernel_launch(void* const* d_in, const int* in_sizes, int n_in,
                              void* d_out, int out_size, void* d_ws, size_t ws_size,
                              hipStream_t stream)
{
  const int*   x   = (const int*)  d_in[0];
  const float* Wxh = (const float*)d_in[1];
  const float* Whh = (const float*)d_in[2];
  const float* bh  = (const float*)d_in[3];
  const float* fcw = (const float*)d_in[4];
  const float* fcb = (const float*)d_in[5];
  float* out = (float*)d_out;

  u16* Hs   = (u16*)d_ws;
  u16* G    = Hs + (size_t)NB * NT * HID;
  u16* hbuf = G + (size_t)NB * NT * NV;
  u32* ctr  = (u32*)(hbuf + 2 * (size_t)NB * HID);
  u16* fcwb = hbuf;   // 512 KB region retired after rnn_persist completes

  hipMemsetAsync(ctr, 0, 8 * 64 * sizeof(u32), stream);

  // 1) persistent RNN: all 512 steps, one kernel
  rnn_persist<<<NBLK, 128, 0, stream>>>(x, Wxh, Whh, bh, Hs, hbuf, ctr);

  // 2) fc_w -> bf16 (into retired hbuf region)
  fcw_cvt<<<256, 256, 0, stream>>>(fcw, fcwb);

  // 3) out_pre (d_out) + G (ws) via MFMA
  gemm_go_mfma<<<(NB * NT) / 64, 256, 0, stream>>>(Hs, fcwb, fcb, out, G);

  // 4) MFMA flash attention in projected space: out += softmax(Hs Hs^T) @ G
  attn_mfma<<<NB * (NT / 64), 256, 0, stream>>>(Hs, G, out);
}

// Round 10
// 2709.586 us; speedup vs baseline: 3.6609x; 1.3124x over previous
//
#include <hip/hip_runtime.h>
#include <cmath>

#define HID 1024
#define NB  128   // batch
#define NT  512   // seq len
#define NV  128   // vocab
#define NBLK 256  // persistent RNN blocks: 8 bg x 32 cg

using u16 = unsigned short;
using u32 = unsigned int;

typedef __attribute__((ext_vector_type(8))) short s16x8;
typedef __attribute__((ext_vector_type(4))) float f32x4;

static __device__ __forceinline__ float bf2f(u16 u) {
  union { u32 i; float f; } v; v.i = ((u32)u) << 16; return v.f;
}
static __device__ __forceinline__ u16 f2bf(float f) {
  union { u32 i; float f; } v; v.f = f;
  u32 r = v.i + 0x7FFFu + ((v.i >> 16) & 1u);   // round-to-nearest-even
  return (u16)(r >> 16);
}

// ---------------------------------------------------------------------------
// Persistent RNN, all 512 steps, 256 blocks = 8 bg (16 batches) x 32 cg
// (32 cols). MALL-coherent exchange (validated rounds 7-8):
//   publish h_t DIRECTLY into Hs[b][t] (never-reused ring -> no dbuf) with
//   sc0 sc1 write-through stores; vmcnt(0); relaxed system-scope counter;
//   consumers bypass-load Hs[b][t-1] into swizzled LDS.
// Round-9 fix: stage mapping (srow=tid>>3, scol=tid&7, stride-128B chunks)
// makes every consecutive 8-lane group of the b128 LDS writes hit 8 distinct
// XOR'd 16B slots -> no 8-way write conflicts (was 2.7e8 cycles/dispatch).
// ---------------------------------------------------------------------------
__global__ __launch_bounds__(128, 1) void rnn_persist(
    const int* __restrict__ x, const float* __restrict__ Wxh,
    const float* __restrict__ Whh, const float* __restrict__ bh,
    u16* __restrict__ Hs, u32* __restrict__ ctr)
{
  const int blk  = blockIdx.x;
  const int bg   = blk & 7;
  const int cg   = blk >> 3;
  const int tid  = threadIdx.x;     // 0..127 (2 waves)
  const int wave = tid >> 6;
  const int lane = tid & 63;
  const int b0   = bg * 16;
  const int c0   = cg * 32;

  __shared__ u16 Wt[32 * 1024];                   // B operand, XOR-swizzled
  __shared__ __align__(16) u16 hstage[16 * 1024]; // A operand, XOR-swizzled

  for (int it = 0; it < 128; ++it) {
    int idx = tid + it * 128;       // 0..16383
    int col = idx & 31;
    int k   = (idx >> 5) * 2;       // k pair
    float w0 = Whh[(size_t)k * HID + c0 + col];
    float w1 = Whh[(size_t)(k + 1) * HID + c0 + col];
    u32 pk = ((u32)f2bf(w1) << 16) | (u32)f2bf(w0);
    u32 byteo = ((u32)col * 2048 + (u32)k * 2) ^ ((u32)(col & 7) << 4);
    *reinterpret_cast<u32*>(reinterpret_cast<char*>(Wt) + byteo) = pk;
  }

  // MFMA fragment geometry (16x16x32 bf16):
  //   A: row = lane&15 (batch m), k-slice = (lane>>4)*8
  //   B: col = lane&15 (out col n), k-slice = (lane>>4)*8
  //   C: n = lane&15, m = (lane>>4)*4 + reg
  const int frow = lane & 15;
  const int koff = (lane >> 4) * 8;
  const int col  = wave * 16 + (lane & 15);
  const int cc   = c0 + col;
  const u32 swz   = (u32)(col & 7) << 4;
  const u32 bbase = (u32)col * 2048 + (u32)koff * 2;
  const char* wtb = reinterpret_cast<const char*>(Wt);
  const char* hsb = reinterpret_cast<const char*>(hstage);
  const u32 abase = (u32)frow * 2048 + (u32)koff * 2;
  const u32 axor  = (u32)(frow & 7) << 4;

  // stage mapping: thread owns batch-row srow, 16B chunks scol*16 + j*128
  const int srow = tid >> 3;        // 0..15
  const int scol = tid & 7;         // 0..7
  const u32 sxor = (u32)(srow & 7) << 4;
  char* sdst = reinterpret_cast<char*>(hstage) + (u32)srow * 2048;

  const float bhv = bh[cc];
  float xr[4];
  #pragma unroll
  for (int r = 0; r < 4; ++r) {
    int m = (lane >> 4) * 4 + r;
    int xt = x[(size_t)(b0 + m) * NT];
    xr[r] = Wxh[(size_t)xt * HID + cc] + bhv;
  }
  __syncthreads();                  // Wt ready

  u32* __restrict__ myctr = ctr + bg * 64;   // 256 B apart per bg

  for (int t = 0; t < NT; ++t) {
    // ---- stage h_{t-1} (from Hs ring) into LDS via bypass loads ----
    if (t > 0) {
      const char* src = reinterpret_cast<const char*>(
          Hs + ((size_t)(b0 + srow) * NT + (t - 1)) * HID) + scol * 16;
      uint4 s[16];
      asm volatile(
        "global_load_dwordx4 %0, %16, off sc0 sc1\n\t"
        "global_load_dwordx4 %1, %16, off offset:128 sc0 sc1\n\t"
        "global_load_dwordx4 %2, %16, off offset:256 sc0 sc1\n\t"
        "global_load_dwordx4 %3, %16, off offset:384 sc0 sc1\n\t"
        "global_load_dwordx4 %4, %16, off offset:512 sc0 sc1\n\t"
        "global_load_dwordx4 %5, %16, off offset:640 sc0 sc1\n\t"
        "global_load_dwordx4 %6, %16, off offset:768 sc0 sc1\n\t"
        "global_load_dwordx4 %7, %16, off offset:896 sc0 sc1\n\t"
        "global_load_dwordx4 %8, %16, off offset:1024 sc0 sc1\n\t"
        "global_load_dwordx4 %9, %16, off offset:1152 sc0 sc1\n\t"
        "global_load_dwordx4 %10, %16, off offset:1280 sc0 sc1\n\t"
        "global_load_dwordx4 %11, %16, off offset:1408 sc0 sc1\n\t"
        "global_load_dwordx4 %12, %16, off offset:1536 sc0 sc1\n\t"
        "global_load_dwordx4 %13, %16, off offset:1664 sc0 sc1\n\t"
        "global_load_dwordx4 %14, %16, off offset:1792 sc0 sc1\n\t"
        "global_load_dwordx4 %15, %16, off offset:1920 sc0 sc1\n\t"
        "s_waitcnt vmcnt(0)"
        : "=&v"(s[0]), "=&v"(s[1]), "=&v"(s[2]), "=&v"(s[3]),
          "=&v"(s[4]), "=&v"(s[5]), "=&v"(s[6]), "=&v"(s[7]),
          "=&v"(s[8]), "=&v"(s[9]), "=&v"(s[10]), "=&v"(s[11]),
          "=&v"(s[12]), "=&v"(s[13]), "=&v"(s[14]), "=&v"(s[15])
        : "v"(src) : "memory");
      __builtin_amdgcn_sched_barrier(0);
      #pragma unroll
      for (int j = 0; j < 16; ++j)
        *reinterpret_cast<uint4*>(sdst +
            (((u32)(scol * 16 + j * 128)) ^ sxor)) = s[j];
    }
    __syncthreads();   // hstage ready

    // ---- S = h_prev @ Wslice via MFMA (K = 1024 = 32 chunks) ----
    f32x4 acc = {0.f, 0.f, 0.f, 0.f};
    if (t > 0) {
      #pragma unroll 8
      for (int kc = 0; kc < 32; ++kc) {
        s16x8 af = *reinterpret_cast<const s16x8*>(hsb + ((abase + (u32)kc * 64) ^ axor));
        s16x8 bf = *reinterpret_cast<const s16x8*>(wtb + ((bbase + (u32)kc * 64) ^ swz));
        acc = __builtin_amdgcn_mfma_f32_16x16x32_bf16(af, bf, acc, 0, 0, 0);
      }
    }

    // ---- epilogue: tanh, publish h_t straight into the Hs ring ----
    #pragma unroll
    for (int r = 0; r < 4; ++r) {
      int m = (lane >> 4) * 4 + r;
      float h = tanhf(acc[r] + xr[r]);
      u16 hb = f2bf(h);
      u16* pa = Hs + ((size_t)(b0 + m) * NT + t) * HID + cc;
      asm volatile("global_store_short %0, %1, off sc0 sc1"
                   :: "v"(pa), "v"((u32)hb) : "memory");
    }
    asm volatile("s_waitcnt vmcnt(0)" ::: "memory");  // publish at MALL
    __syncthreads();

    if (tid == 0 && t < NT - 1)
      __hip_atomic_fetch_add(myctr, 1u, __ATOMIC_RELAXED, __HIP_MEMORY_SCOPE_SYSTEM);

    // ---- overlap the spin: prefetch next xe (L2-hot) ----
    if (t < NT - 1) {
      #pragma unroll
      for (int r = 0; r < 4; ++r) {
        int m = (lane >> 4) * 4 + r;
        int xt = x[(size_t)(b0 + m) * NT + t + 1];
        xr[r] = Wxh[(size_t)xt * HID + cc] + bhv;
      }
      if (tid == 0) {
        const u32 target = 32u * (u32)(t + 1);
        while (__hip_atomic_load(myctr, __ATOMIC_RELAXED, __HIP_MEMORY_SCOPE_SYSTEM) < target)
          __builtin_amdgcn_s_sleep(1);
      }
    }
    __syncthreads();
  }
}

// ---------------------------------------------------------------------------
// fcw_cvt: fc_w f32 [128][2048] -> bf16 copy (into the spare ws region).
// ---------------------------------------------------------------------------
__global__ __launch_bounds__(256) void fcw_cvt(
    const float* __restrict__ fcw, u16* __restrict__ fcwb)
{
  int i = (blockIdx.x * 256 + threadIdx.x) * 4;   // 262144 elems / 4
  float4 f = *reinterpret_cast<const float4*>(fcw + i);
  uint2 o;
  o.x = (u32)f2bf(f.x) | ((u32)f2bf(f.y) << 16);
  o.y = (u32)f2bf(f.z) | ((u32)f2bf(f.w) << 16);
  *reinterpret_cast<uint2*>(fcwb + i) = o;
}

// ---------------------------------------------------------------------------
// gemm_go_mfma: rows = (b,t); both halves share A = Hs row (k=0..1023):
//   n<8 : outpre[row][n*16+c] = Hs[row] . fcw[v=n*16+c][0:1024]   + fcb
//   n>=8: G[row][(n-8)*16+c]  = Hs[row] . fcw[v][1024:2048]  (bf16)
// ---------------------------------------------------------------------------
__global__ __launch_bounds__(256) void gemm_go_mfma(
    const u16* __restrict__ Hs, const u16* __restrict__ fcwb,
    const float* __restrict__ fcb, float* __restrict__ outpre,
    u16* __restrict__ G)
{
  const int row0 = blockIdx.x * 64;
  const int w    = threadIdx.x >> 6;
  const int lane = threadIdx.x & 63;
  const int frow = lane & 15;
  const int koff = (lane >> 4) * 8;
  const int g4   = lane >> 4;

  f32x4 acc[16] = {};
  const u16* ap0 = Hs + (size_t)(row0 + w * 16 + frow) * HID + koff;

  for (int kc = 0; kc < 32; ++kc) {
    s16x8 a = *reinterpret_cast<const s16x8*>(ap0 + kc * 32);
    #pragma unroll
    for (int n = 0; n < 16; ++n) {
      int v = (n & 7) * 16 + frow;
      int kb = (n >> 3) * 1024 + kc * 32 + koff;
      s16x8 bf = *reinterpret_cast<const s16x8*>(fcwb + (size_t)v * 2048 + kb);
      acc[n] = __builtin_amdgcn_mfma_f32_16x16x32_bf16(a, bf, acc[n], 0, 0, 0);
    }
  }

  #pragma unroll
  for (int n = 0; n < 16; ++n) {
    int v = (n & 7) * 16 + frow;
    float fb = (n < 8) ? fcb[v] : 0.f;
    #pragma unroll
    for (int r = 0; r < 4; ++r) {
      size_t row = (size_t)(row0 + w * 16 + g4 * 4 + r);
      if (n < 8) outpre[row * NV + v] = acc[n][r] + fb;
      else       G[row * NV + v]      = f2bf(acc[n][r]);
    }
  }
}

// ---------------------------------------------------------------------------
// attn_mfma: block = (b, 64 q-rows), 4 waves x 16 rows (unchanged, r8-pass).
// ---------------------------------------------------------------------------
__global__ __launch_bounds__(256) void attn_mfma(
    const u16* __restrict__ Hs, const u16* __restrict__ G,
    float* __restrict__ out)
{
  const int blk  = blockIdx.x;        // 128 b x 8 q-tiles
  const int b    = blk >> 3;
  const int q0   = (blk & 7) * 64;
  const int tid  = threadIdx.x;
  const int w    = tid >> 6;
  const int lane = tid & 63;
  const int frow = lane & 15;
  const int koff = (lane >> 4) * 8;
  const int g4   = lane >> 4;

  __shared__ __align__(16) u16 Kc[64 * 128];   // 16 KB, swizzled
  __shared__ __align__(16) u16 Gt[128 * 64];   // 16 KB, swizzled (v-major)
  __shared__ __align__(16) u16 Pl[64 * 64];    // 8 KB, swizzled

  const u16* __restrict__ Hb = Hs + (size_t)b * NT * HID;
  const u16* __restrict__ Gb = G  + (size_t)b * NT * NV;
  const char* kcb = reinterpret_cast<const char*>(Kc);
  const char* gtb = reinterpret_cast<const char*>(Gt);
  const char* plb = reinterpret_cast<const char*>(Pl);

  float m[4], l[4];
  #pragma unroll
  for (int r = 0; r < 4; ++r) { m[r] = -INFINITY; l[r] = 0.f; }
  f32x4 accO[8] = {};

  for (int st = 0; st < 8; ++st) {
    const int s0 = st * 64;
    __syncthreads();                       // prev tile's Gt/Pl consumers done

    // ---- stage Gt[v][s] (transposed G tile) ----
    for (int it = 0; it < 32; ++it) {
      int idx = tid + it * 256;            // 0..8191
      int s = idx >> 7, v = idx & 127;
      u16 gv = Gb[(size_t)(s0 + s) * NV + v];
      *reinterpret_cast<u16*>(const_cast<char*>(gtb) +
          (((u32)v * 128 + (u32)s * 2) ^ ((u32)(v & 7) << 4))) = gv;
    }

    // ---- S = Q K^T accumulation over k-chunks of 128 ----
    f32x4 sacc[4] = {};
    for (int kc = 0; kc < 8; ++kc) {
      __syncthreads();                     // prev Kc consumed
      #pragma unroll
      for (int i = 0; i < 4; ++i) {
        int idx = tid + i * 256;           // 0..1023
        int row = idx >> 4, cg = idx & 15;
        uint4 kd = *reinterpret_cast<const uint4*>(
            Hb + (size_t)(s0 + row) * HID + kc * 128 + cg * 8);
        *reinterpret_cast<uint4*>(const_cast<char*>(kcb) +
            (((u32)row * 256 + (u32)cg * 16) ^ ((u32)(row & 7) << 4))) = kd;
      }
      __syncthreads();

      s16x8 aq[4];
      const u16* qp = Hb + (size_t)(q0 + w * 16 + frow) * HID + kc * 128 + koff;
      #pragma unroll
      for (int ks = 0; ks < 4; ++ks)
        aq[ks] = *reinterpret_cast<const s16x8*>(qp + ks * 32);

      #pragma unroll
      for (int ks = 0; ks < 4; ++ks) {
        #pragma unroll
        for (int n = 0; n < 4; ++n) {
          int srow = n * 16 + frow;
          s16x8 bk = *reinterpret_cast<const s16x8*>(kcb +
              (((u32)srow * 256 + (u32)(ks * 32 + koff) * 2) ^ ((u32)(srow & 7) << 4)));
          sacc[n] = __builtin_amdgcn_mfma_f32_16x16x32_bf16(aq[ks], bk, sacc[n], 0, 0, 0);
        }
      }
    }

    // ---- online softmax (rows replicated across each 16-lane group) ----
    float p[4][4];
    float sc[4];
    #pragma unroll
    for (int r = 0; r < 4; ++r) {
      float t = fmaxf(fmaxf(sacc[0][r], sacc[1][r]), fmaxf(sacc[2][r], sacc[3][r]));
      t = fmaxf(t, __shfl_xor(t, 1));
      t = fmaxf(t, __shfl_xor(t, 2));
      t = fmaxf(t, __shfl_xor(t, 4));
      t = fmaxf(t, __shfl_xor(t, 8));
      float mn = fmaxf(m[r], t);
      sc[r] = __expf(m[r] - mn);
      float rs = 0.f;
      #pragma unroll
      for (int n = 0; n < 4; ++n) { p[n][r] = __expf(sacc[n][r] - mn); rs += p[n][r]; }
      rs += __shfl_xor(rs, 1);
      rs += __shfl_xor(rs, 2);
      rs += __shfl_xor(rs, 4);
      rs += __shfl_xor(rs, 8);
      l[r] = l[r] * sc[r] + rs;
      m[r] = mn;
    }
    #pragma unroll
    for (int v8 = 0; v8 < 8; ++v8)
      #pragma unroll
      for (int r = 0; r < 4; ++r) accO[v8][r] *= sc[r];

    // ---- P -> per-wave LDS tile (bf16, swizzled) ----
    #pragma unroll
    for (int n = 0; n < 4; ++n) {
      int s = n * 16 + frow;
      #pragma unroll
      for (int r = 0; r < 4; ++r) {
        int q = w * 16 + g4 * 4 + r;
        *reinterpret_cast<u16*>(const_cast<char*>(plb) +
            (((u32)q * 128 + (u32)s * 2) ^ ((u32)(q & 7) << 4))) = f2bf(p[n][r]);
      }
    }
    asm volatile("s_waitcnt lgkmcnt(0)" ::: "memory");   // own-wave P writes done
    __builtin_amdgcn_sched_barrier(0);

    // ---- PV: O += P . Gt ----
    #pragma unroll
    for (int ss = 0; ss < 2; ++ss) {
      int qrow = w * 16 + frow;
      s16x8 ap = *reinterpret_cast<const s16x8*>(plb +
          (((u32)qrow * 128 + (u32)(ss * 32 + koff) * 2) ^ ((u32)(qrow & 7) << 4)));
      #pragma unroll
      for (int v8 = 0; v8 < 8; ++v8) {
        int vrow = v8 * 16 + frow;
        s16x8 bg = *reinterpret_cast<const s16x8*>(gtb +
            (((u32)vrow * 128 + (u32)(ss * 32 + koff) * 2) ^ ((u32)(vrow & 7) << 4)));
        accO[v8] = __builtin_amdgcn_mfma_f32_16x16x32_bf16(ap, bg, accO[v8], 0, 0, 0);
      }
    }
  }

  // ---- epilogue: out += accO / l ----
  float inv[4];
  #pragma unroll
  for (int r = 0; r < 4; ++r) inv[r] = 1.f / l[r];
  #pragma unroll
  for (int v8 = 0; v8 < 8; ++v8) {
    int c = v8 * 16 + frow;
    #pragma unroll
    for (int r = 0; r < 4; ++r) {
      size_t row = (size_t)b * NT + q0 + w * 16 + g4 * 4 + r;
      out[row * NV + c] += accO[v8][r] * inv[r];
    }
  }
}

// ---------------------------------------------------------------------------
// Workspace layout (~144.6 MiB):
//   Hs   bf16 [128][512][1024]  134,217,728 B   (doubles as the h ring)
//   G    bf16 [128][512][128]    16,777,216 B
//   fcwb bf16 [128][2048]           524,288 B
//   ctr  u32  [8*64]                  2,048 B
// ---------------------------------------------------------------------------
extern "C" void kernel_launch(void* const* d_in, const int* in_sizes, int n_in,
                              void* d_out, int out_size, void* d_ws, size_t ws_size,
                              hipStream_t stream)
{
  const int*   x   = (const int*)  d_in[0];
  const float* Wxh = (const float*)d_in[1];
  const float* Whh = (const float*)d_in[2];
  const float* bh  = (const float*)d_in[3];
  const float* fcw = (const float*)d_in[4];
  const float* fcb = (const float*)d_in[5];
  float* out = (float*)d_out;

  u16* Hs   = (u16*)d_ws;
  u16* G    = Hs + (size_t)NB * NT * HID;
  u16* fcwb = G + (size_t)NB * NT * NV;
  u32* ctr  = (u32*)(fcwb + (size_t)NV * 2 * HID);

  hipMemsetAsync(ctr, 0, 8 * 64 * sizeof(u32), stream);

  // 1) persistent RNN: all 512 steps, one kernel; publishes h into Hs ring
  rnn_persist<<<NBLK, 128, 0, stream>>>(x, Wxh, Whh, bh, Hs, ctr);

  // 2) fc_w -> bf16
  fcw_cvt<<<256, 256, 0, stream>>>(fcw, fcwb);

  // 3) out_pre (d_out) + G (ws) via MFMA
  gemm_go_mfma<<<(NB * NT) / 64, 256, 0, stream>>>(Hs, fcwb, fcb, out, G);

  // 4) MFMA flash attention in projected space: out += softmax(Hs Hs^T) @ G
  attn_mfma<<<NB * (NT / 64), 256, 0, stream>>>(Hs, G, out);
}

// Round 11
// 2542.095 us; speedup vs baseline: 3.9021x; 1.0659x over previous
//
#include <hip/hip_runtime.h>
#include <cmath>

#define HID 1024
#define NB  128   // batch
#define NT  512   // seq len
#define NV  128   // vocab
#define NBLK 256  // persistent RNN blocks: 8 bg x 32 cg

using u16 = unsigned short;
using u32 = unsigned int;

typedef __attribute__((ext_vector_type(8))) short s16x8;
typedef __attribute__((ext_vector_type(4))) float f32x4;

static __device__ __forceinline__ float bf2f(u16 u) {
  union { u32 i; float f; } v; v.i = ((u32)u) << 16; return v.f;
}
static __device__ __forceinline__ u16 f2bf(float f) {
  union { u32 i; float f; } v; v.f = f;
  u32 r = v.i + 0x7FFFu + ((v.i >> 16) & 1u);   // round-to-nearest-even
  return (u16)(r >> 16);
}
// tanh via HW exp+rcp: 1 - 2/(1+e^{2x}); correct limits at +/-inf, ~1e-6 abs.
static __device__ __forceinline__ float fast_tanh(float x) {
  float e = __expf(2.f * x);
  return 1.f - 2.f * __builtin_amdgcn_rcpf(1.f + e);
}

// ---------------------------------------------------------------------------
// Persistent RNN, all 512 steps, 256 blocks = 8 bg (16 batches) x 32 cg
// (32 cols). MALL-coherent exchange (validated rounds 7-10):
//   publish h_t into Hs[b][t] ring via sc0 sc1 write-through stores; block-
//   wide vmcnt(0)+barrier; then publish per-block FLAG (own 128B line,
//   plain store, no RMW) -- round-11 change: replaces the 32-way atomicAdd
//   on a shared counter line (RMW serialization ~1-2k cy/step).
//   Consumers: 64 lanes poll flag[bg][lane&31] in parallel (bypass loads,
//   one MALL RT per iteration), then bypass-load h into swizzled LDS.
// ---------------------------------------------------------------------------
__global__ __launch_bounds__(128, 1) void rnn_persist(
    const int* __restrict__ x, const float* __restrict__ Wxh,
    const float* __restrict__ Whh, const float* __restrict__ bh,
    u16* __restrict__ Hs, u32* __restrict__ flags)
{
  const int blk  = blockIdx.x;
  const int bg   = blk & 7;
  const int cg   = blk >> 3;
  const int tid  = threadIdx.x;     // 0..127 (2 waves)
  const int wave = tid >> 6;
  const int lane = tid & 63;
  const int b0   = bg * 16;
  const int c0   = cg * 32;

  __shared__ u16 Wt[32 * 1024];                   // B operand, XOR-swizzled
  __shared__ __align__(16) u16 hstage[16 * 1024]; // A operand, XOR-swizzled

  for (int it = 0; it < 128; ++it) {
    int idx = tid + it * 128;       // 0..16383
    int col = idx & 31;
    int k   = (idx >> 5) * 2;       // k pair
    float w0 = Whh[(size_t)k * HID + c0 + col];
    float w1 = Whh[(size_t)(k + 1) * HID + c0 + col];
    u32 pk = ((u32)f2bf(w1) << 16) | (u32)f2bf(w0);
    u32 byteo = ((u32)col * 2048 + (u32)k * 2) ^ ((u32)(col & 7) << 4);
    *reinterpret_cast<u32*>(reinterpret_cast<char*>(Wt) + byteo) = pk;
  }

  // MFMA fragment geometry (16x16x32 bf16):
  //   A: row = lane&15 (batch m), k-slice = (lane>>4)*8
  //   B: col = lane&15 (out col n), k-slice = (lane>>4)*8
  //   C: n = lane&15, m = (lane>>4)*4 + reg
  const int frow = lane & 15;
  const int koff = (lane >> 4) * 8;
  const int col  = wave * 16 + (lane & 15);
  const int cc   = c0 + col;
  const u32 swz   = (u32)(col & 7) << 4;
  const u32 bbase = (u32)col * 2048 + (u32)koff * 2;
  const char* wtb = reinterpret_cast<const char*>(Wt);
  const char* hsb = reinterpret_cast<const char*>(hstage);
  const u32 abase = (u32)frow * 2048 + (u32)koff * 2;
  const u32 axor  = (u32)(frow & 7) << 4;

  // stage mapping: thread owns batch-row srow, 16B chunks scol*16 + j*128
  const int srow = tid >> 3;        // 0..15
  const int scol = tid & 7;         // 0..7
  const u32 sxor = (u32)(srow & 7) << 4;
  char* sdst = reinterpret_cast<char*>(hstage) + (u32)srow * 2048;

  // flag addresses: 32 flags per bg, 128 B apart (32 u32 stride)
  u32* flag_self = flags + (u32)bg * 1024 + (u32)cg * 32;
  const u32* flag_poll = flags + (u32)bg * 1024 + (u32)(lane & 31) * 32;

  const float bhv = bh[cc];
  float xr[4];
  #pragma unroll
  for (int r = 0; r < 4; ++r) {
    int m = (lane >> 4) * 4 + r;
    int xt = x[(size_t)(b0 + m) * NT];
    xr[r] = Wxh[(size_t)xt * HID + cc] + bhv;
  }
  __syncthreads();                  // Wt ready

  for (int t = 0; t < NT; ++t) {
    // ---- stage h_{t-1} (from Hs ring) into LDS via bypass loads ----
    if (t > 0) {
      const char* src = reinterpret_cast<const char*>(
          Hs + ((size_t)(b0 + srow) * NT + (t - 1)) * HID) + scol * 16;
      uint4 s[16];
      asm volatile(
        "global_load_dwordx4 %0, %16, off sc0 sc1\n\t"
        "global_load_dwordx4 %1, %16, off offset:128 sc0 sc1\n\t"
        "global_load_dwordx4 %2, %16, off offset:256 sc0 sc1\n\t"
        "global_load_dwordx4 %3, %16, off offset:384 sc0 sc1\n\t"
        "global_load_dwordx4 %4, %16, off offset:512 sc0 sc1\n\t"
        "global_load_dwordx4 %5, %16, off offset:640 sc0 sc1\n\t"
        "global_load_dwordx4 %6, %16, off offset:768 sc0 sc1\n\t"
        "global_load_dwordx4 %7, %16, off offset:896 sc0 sc1\n\t"
        "global_load_dwordx4 %8, %16, off offset:1024 sc0 sc1\n\t"
        "global_load_dwordx4 %9, %16, off offset:1152 sc0 sc1\n\t"
        "global_load_dwordx4 %10, %16, off offset:1280 sc0 sc1\n\t"
        "global_load_dwordx4 %11, %16, off offset:1408 sc0 sc1\n\t"
        "global_load_dwordx4 %12, %16, off offset:1536 sc0 sc1\n\t"
        "global_load_dwordx4 %13, %16, off offset:1664 sc0 sc1\n\t"
        "global_load_dwordx4 %14, %16, off offset:1792 sc0 sc1\n\t"
        "global_load_dwordx4 %15, %16, off offset:1920 sc0 sc1\n\t"
        "s_waitcnt vmcnt(0)"
        : "=&v"(s[0]), "=&v"(s[1]), "=&v"(s[2]), "=&v"(s[3]),
          "=&v"(s[4]), "=&v"(s[5]), "=&v"(s[6]), "=&v"(s[7]),
          "=&v"(s[8]), "=&v"(s[9]), "=&v"(s[10]), "=&v"(s[11]),
          "=&v"(s[12]), "=&v"(s[13]), "=&v"(s[14]), "=&v"(s[15])
        : "v"(src) : "memory");
      __builtin_amdgcn_sched_barrier(0);
      #pragma unroll
      for (int j = 0; j < 16; ++j)
        *reinterpret_cast<uint4*>(sdst +
            (((u32)(scol * 16 + j * 128)) ^ sxor)) = s[j];
    }
    __syncthreads();   // hstage ready

    // ---- S = h_prev @ Wslice via MFMA (K = 1024 = 32 chunks) ----
    f32x4 acc = {0.f, 0.f, 0.f, 0.f};
    if (t > 0) {
      #pragma unroll 8
      for (int kc = 0; kc < 32; ++kc) {
        s16x8 af = *reinterpret_cast<const s16x8*>(hsb + ((abase + (u32)kc * 64) ^ axor));
        s16x8 bf = *reinterpret_cast<const s16x8*>(wtb + ((bbase + (u32)kc * 64) ^ swz));
        acc = __builtin_amdgcn_mfma_f32_16x16x32_bf16(af, bf, acc, 0, 0, 0);
      }
    }

    // ---- epilogue: tanh, publish h_t straight into the Hs ring ----
    #pragma unroll
    for (int r = 0; r < 4; ++r) {
      int m = (lane >> 4) * 4 + r;
      float h = fast_tanh(acc[r] + xr[r]);
      u16 hb = f2bf(h);
      u16* pa = Hs + ((size_t)(b0 + m) * NT + t) * HID + cc;
      asm volatile("global_store_short %0, %1, off sc0 sc1"
                   :: "v"(pa), "v"((u32)hb) : "memory");
    }
    asm volatile("s_waitcnt vmcnt(0)" ::: "memory");  // own stores at MALL
    __syncthreads();   // ALL threads' h_t drained (and hstage reads done)

    if (t < NT - 1) {
      // publish our flag = t+1 (own 128B line, plain write-through store)
      if (tid == 0) {
        asm volatile("global_store_dword %0, %1, off sc0 sc1"
                     :: "v"(flag_self), "v"((u32)(t + 1)) : "memory");
      }
      // overlap with the flag RT: prefetch next xe (L2-hot cached loads)
      #pragma unroll
      for (int r = 0; r < 4; ++r) {
        int m = (lane >> 4) * 4 + r;
        int xt = x[(size_t)(b0 + m) * NT + t + 1];
        xr[r] = Wxh[(size_t)xt * HID + cc] + bhv;
      }
      // parallel poll: 64 lanes cover the 32 producer flags (2 lanes/flag)
      const u32 target = (u32)(t + 1);
      u32 f;
      do {
        asm volatile("global_load_dword %0, %1, off sc0 sc1\n\t"
                     "s_waitcnt vmcnt(0)"
                     : "=&v"(f) : "v"(flag_poll) : "memory");
      } while (__any((int)(f < target)));
      // per-wave gate passed; next stage loads follow (volatile asm order)
    }
  }
}

// ---------------------------------------------------------------------------
// fcw_cvt: fc_w f32 [128][2048] -> bf16 copy (into the spare ws region).
// ---------------------------------------------------------------------------
__global__ __launch_bounds__(256) void fcw_cvt(
    const float* __restrict__ fcw, u16* __restrict__ fcwb)
{
  int i = (blockIdx.x * 256 + threadIdx.x) * 4;   // 262144 elems / 4
  float4 f = *reinterpret_cast<const float4*>(fcw + i);
  uint2 o;
  o.x = (u32)f2bf(f.x) | ((u32)f2bf(f.y) << 16);
  o.y = (u32)f2bf(f.z) | ((u32)f2bf(f.w) << 16);
  *reinterpret_cast<uint2*>(fcwb + i) = o;
}

// ---------------------------------------------------------------------------
// gemm_go_mfma: rows = (b,t); both halves share A = Hs row (k=0..1023):
//   n<8 : outpre[row][n*16+c] = Hs[row] . fcw[v=n*16+c][0:1024]   + fcb
//   n>=8: G[row][(n-8)*16+c]  = Hs[row] . fcw[v][1024:2048]  (bf16)
// ---------------------------------------------------------------------------
__global__ __launch_bounds__(256) void gemm_go_mfma(
    const u16* __restrict__ Hs, const u16* __restrict__ fcwb,
    const float* __restrict__ fcb, float* __restrict__ outpre,
    u16* __restrict__ G)
{
  const int row0 = blockIdx.x * 64;
  const int w    = threadIdx.x >> 6;
  const int lane = threadIdx.x & 63;
  const int frow = lane & 15;
  const int koff = (lane >> 4) * 8;
  const int g4   = lane >> 4;

  f32x4 acc[16] = {};
  const u16* ap0 = Hs + (size_t)(row0 + w * 16 + frow) * HID + koff;

  for (int kc = 0; kc < 32; ++kc) {
    s16x8 a = *reinterpret_cast<const s16x8*>(ap0 + kc * 32);
    #pragma unroll
    for (int n = 0; n < 16; ++n) {
      int v = (n & 7) * 16 + frow;
      int kb = (n >> 3) * 1024 + kc * 32 + koff;
      s16x8 bf = *reinterpret_cast<const s16x8*>(fcwb + (size_t)v * 2048 + kb);
      acc[n] = __builtin_amdgcn_mfma_f32_16x16x32_bf16(a, bf, acc[n], 0, 0, 0);
    }
  }

  #pragma unroll
  for (int n = 0; n < 16; ++n) {
    int v = (n & 7) * 16 + frow;
    float fb = (n < 8) ? fcb[v] : 0.f;
    #pragma unroll
    for (int r = 0; r < 4; ++r) {
      size_t row = (size_t)(row0 + w * 16 + g4 * 4 + r);
      if (n < 8) outpre[row * NV + v] = acc[n][r] + fb;
      else       G[row * NV + v]      = f2bf(acc[n][r]);
    }
  }
}

// ---------------------------------------------------------------------------
// attn_mfma: block = (b, 64 q-rows), 4 waves x 16 rows (unchanged, r8-pass).
// ---------------------------------------------------------------------------
__global__ __launch_bounds__(256) void attn_mfma(
    const u16* __restrict__ Hs, const u16* __restrict__ G,
    float* __restrict__ out)
{
  const int blk  = blockIdx.x;        // 128 b x 8 q-tiles
  const int b    = blk >> 3;
  const int q0   = (blk & 7) * 64;
  const int tid  = threadIdx.x;
  const int w    = tid >> 6;
  const int lane = tid & 63;
  const int frow = lane & 15;
  const int koff = (lane >> 4) * 8;
  const int g4   = lane >> 4;

  __shared__ __align__(16) u16 Kc[64 * 128];   // 16 KB, swizzled
  __shared__ __align__(16) u16 Gt[128 * 64];   // 16 KB, swizzled (v-major)
  __shared__ __align__(16) u16 Pl[64 * 64];    // 8 KB, swizzled

  const u16* __restrict__ Hb = Hs + (size_t)b * NT * HID;
  const u16* __restrict__ Gb = G  + (size_t)b * NT * NV;
  const char* kcb = reinterpret_cast<const char*>(Kc);
  const char* gtb = reinterpret_cast<const char*>(Gt);
  const char* plb = reinterpret_cast<const char*>(Pl);

  float m[4], l[4];
  #pragma unroll
  for (int r = 0; r < 4; ++r) { m[r] = -INFINITY; l[r] = 0.f; }
  f32x4 accO[8] = {};

  for (int st = 0; st < 8; ++st) {
    const int s0 = st * 64;
    __syncthreads();                       // prev tile's Gt/Pl consumers done

    // ---- stage Gt[v][s] (transposed G tile) ----
    for (int it = 0; it < 32; ++it) {
      int idx = tid + it * 256;            // 0..8191
      int s = idx >> 7, v = idx & 127;
      u16 gv = Gb[(size_t)(s0 + s) * NV + v];
      *reinterpret_cast<u16*>(const_cast<char*>(gtb) +
          (((u32)v * 128 + (u32)s * 2) ^ ((u32)(v & 7) << 4))) = gv;
    }

    // ---- S = Q K^T accumulation over k-chunks of 128 ----
    f32x4 sacc[4] = {};
    for (int kc = 0; kc < 8; ++kc) {
      __syncthreads();                     // prev Kc consumed
      #pragma unroll
      for (int i = 0; i < 4; ++i) {
        int idx = tid + i * 256;           // 0..1023
        int row = idx >> 4, cg = idx & 15;
        uint4 kd = *reinterpret_cast<const uint4*>(
            Hb + (size_t)(s0 + row) * HID + kc * 128 + cg * 8);
        *reinterpret_cast<uint4*>(const_cast<char*>(kcb) +
            (((u32)row * 256 + (u32)cg * 16) ^ ((u32)(row & 7) << 4))) = kd;
      }
      __syncthreads();

      s16x8 aq[4];
      const u16* qp = Hb + (size_t)(q0 + w * 16 + frow) * HID + kc * 128 + koff;
      #pragma unroll
      for (int ks = 0; ks < 4; ++ks)
        aq[ks] = *reinterpret_cast<const s16x8*>(qp + ks * 32);

      #pragma unroll
      for (int ks = 0; ks < 4; ++ks) {
        #pragma unroll
        for (int n = 0; n < 4; ++n) {
          int srow = n * 16 + frow;
          s16x8 bk = *reinterpret_cast<const s16x8*>(kcb +
              (((u32)srow * 256 + (u32)(ks * 32 + koff) * 2) ^ ((u32)(srow & 7) << 4)));
          sacc[n] = __builtin_amdgcn_mfma_f32_16x16x32_bf16(aq[ks], bk, sacc[n], 0, 0, 0);
        }
      }
    }

    // ---- online softmax (rows replicated across each 16-lane group) ----
    float p[4][4];
    float sc[4];
    #pragma unroll
    for (int r = 0; r < 4; ++r) {
      float t = fmaxf(fmaxf(sacc[0][r], sacc[1][r]), fmaxf(sacc[2][r], sacc[3][r]));
      t = fmaxf(t, __shfl_xor(t, 1));
      t = fmaxf(t, __shfl_xor(t, 2));
      t = fmaxf(t, __shfl_xor(t, 4));
      t = fmaxf(t, __shfl_xor(t, 8));
      float mn = fmaxf(m[r], t);
      sc[r] = __expf(m[r] - mn);
      float rs = 0.f;
      #pragma unroll
      for (int n = 0; n < 4; ++n) { p[n][r] = __expf(sacc[n][r] - mn); rs += p[n][r]; }
      rs += __shfl_xor(rs, 1);
      rs += __shfl_xor(rs, 2);
      rs += __shfl_xor(rs, 4);
      rs += __shfl_xor(rs, 8);
      l[r] = l[r] * sc[r] + rs;
      m[r] = mn;
    }
    #pragma unroll
    for (int v8 = 0; v8 < 8; ++v8)
      #pragma unroll
      for (int r = 0; r < 4; ++r) accO[v8][r] *= sc[r];

    // ---- P -> per-wave LDS tile (bf16, swizzled) ----
    #pragma unroll
    for (int n = 0; n < 4; ++n) {
      int s = n * 16 + frow;
      #pragma unroll
      for (int r = 0; r < 4; ++r) {
        int q = w * 16 + g4 * 4 + r;
        *reinterpret_cast<u16*>(const_cast<char*>(plb) +
            (((u32)q * 128 + (u32)s * 2) ^ ((u32)(q & 7) << 4))) = f2bf(p[n][r]);
      }
    }
    asm volatile("s_waitcnt lgkmcnt(0)" ::: "memory");   // own-wave P writes done
    __builtin_amdgcn_sched_barrier(0);

    // ---- PV: O += P . Gt ----
    #pragma unroll
    for (int ss = 0; ss < 2; ++ss) {
      int qrow = w * 16 + frow;
      s16x8 ap = *reinterpret_cast<const s16x8*>(plb +
          (((u32)qrow * 128 + (u32)(ss * 32 + koff) * 2) ^ ((u32)(qrow & 7) << 4)));
      #pragma unroll
      for (int v8 = 0; v8 < 8; ++v8) {
        int vrow = v8 * 16 + frow;
        s16x8 bg = *reinterpret_cast<const s16x8*>(gtb +
            (((u32)vrow * 128 + (u32)(ss * 32 + koff) * 2) ^ ((u32)(vrow & 7) << 4)));
        accO[v8] = __builtin_amdgcn_mfma_f32_16x16x32_bf16(ap, bg, accO[v8], 0, 0, 0);
      }
    }
  }

  // ---- epilogue: out += accO / l ----
  float inv[4];
  #pragma unroll
  for (int r = 0; r < 4; ++r) inv[r] = 1.f / l[r];
  #pragma unroll
  for (int v8 = 0; v8 < 8; ++v8) {
    int c = v8 * 16 + frow;
    #pragma unroll
    for (int r = 0; r < 4; ++r) {
      size_t row = (size_t)b * NT + q0 + w * 16 + g4 * 4 + r;
      out[row * NV + c] += accO[v8][r] * inv[r];
    }
  }
}

// ---------------------------------------------------------------------------
// Workspace layout (~151.6 MiB):
//   Hs    bf16 [128][512][1024]  134,217,728 B   (doubles as the h ring)
//   G     bf16 [128][512][128]    16,777,216 B
//   fcwb  bf16 [128][2048]           524,288 B
//   flags u32  [8][32] @128B spacing  32,768 B
// ---------------------------------------------------------------------------
extern "C" void kernel_launch(void* const* d_in, const int* in_sizes, int n_in,
                              void* d_out, int out_size, void* d_ws, size_t ws_size,
                              hipStream_t stream)
{
  const int*   x   = (const int*)  d_in[0];
  const float* Wxh = (const float*)d_in[1];
  const float* Whh = (const float*)d_in[2];
  const float* bh  = (const float*)d_in[3];
  const float* fcw = (const float*)d_in[4];
  const float* fcb = (const float*)d_in[5];
  float* out = (float*)d_out;

  u16* Hs    = (u16*)d_ws;
  u16* G     = Hs + (size_t)NB * NT * HID;
  u16* fcwb  = G + (size_t)NB * NT * NV;
  u32* flags = (u32*)(fcwb + (size_t)NV * 2 * HID);

  // zero the per-block flags (ws is re-poisoned before every launch)
  hipMemsetAsync(flags, 0, 8 * 1024 * sizeof(u32), stream);

  // 1) persistent RNN: all 512 steps, one kernel; publishes h into Hs ring
  rnn_persist<<<NBLK, 128, 0, stream>>>(x, Wxh, Whh, bh, Hs, flags);

  // 2) fc_w -> bf16
  fcw_cvt<<<256, 256, 0, stream>>>(fcw, fcwb);

  // 3) out_pre (d_out) + G (ws) via MFMA
  gemm_go_mfma<<<(NB * NT) / 64, 256, 0, stream>>>(Hs, fcwb, fcb, out, G);

  // 4) MFMA flash attention in projected space: out += softmax(Hs Hs^T) @ G
  attn_mfma<<<NB * (NT / 64), 256, 0, stream>>>(Hs, G, out);
}